// Round 1
// baseline (290.734 us; speedup 1.0000x reference)
//
#include <hip/hip_runtime.h>
#include <hip/hip_bf16.h>

// Problem constants
#define NN    16      // batch
#define INC   32
#define INN   65536
#define OUTC  32
#define OUTN  8192
#define MAXD  16
#define NC    512     // NN*INC

// ---------------------------------------------------------------------------
// Kernel A: feat[j][r] = x[r][j] * weight[r&31][j], stored bf16.
// x is (512, 65536) row-major; feat is (65536, 512) row-major in d_ws.
// 64x64 tile transpose through LDS.
// ---------------------------------------------------------------------------
__global__ __launch_bounds__(256) void transpose_scale_kernel(
    const float* __restrict__ x,
    const float* __restrict__ weight,
    __hip_bfloat16* __restrict__ feat)
{
    __shared__ float tile[64][65];   // +1 pad
    const int l  = threadIdx.x;          // 0..255
    const int j0 = blockIdx.x * 64;      // 0..65535 step 64  (1024 blocks)
    const int r0 = blockIdx.y * 64;      // 0..511   step 64  (8 blocks)

    // Read phase: 16 iters x 4 rows of 64 consecutive j (coalesced).
    #pragma unroll
    for (int it = 0; it < 16; ++it) {
        int idx = it * 256 + l;
        int rl  = idx >> 6;          // 0..63
        int jl  = idx & 63;
        int r   = r0 + rl;
        int j   = j0 + jl;
        int c   = r & 31;
        tile[rl][jl] = x[(size_t)r * INN + j] * weight[(size_t)c * INN + j];
    }
    __syncthreads();

    // Write phase: each thread packs 2 consecutive r into one bf16x2.
    #pragma unroll
    for (int it = 0; it < 8; ++it) {
        int jl = it * 8 + (l >> 5);  // 0..63
        int rp = l & 31;             // r = 2*rp, 2*rp+1
        float v0 = tile[2 * rp][jl];
        float v1 = tile[2 * rp + 1][jl];
        __hip_bfloat162 p;
        p.x = __float2bfloat16(v0);
        p.y = __float2bfloat16(v1);
        *reinterpret_cast<__hip_bfloat162*>(
            feat + (size_t)(j0 + jl) * NC + (r0 + 2 * rp)) = p;
    }
}

// ---------------------------------------------------------------------------
// Kernel B: one block per OTILE=16 output nodes.
//   pooled[o][nc] = sum_d  w[o,d] * feat[A[o,d]][nc]           (gather phase)
//   out[n][dout][o] = sum_c pooled[o][n*32+c]*ct[dout][c]
//                     + ct_bias[dout] + bias[dout][o]          (gemm phase)
// ---------------------------------------------------------------------------
#define OTILE 16

__global__ __launch_bounds__(256) void gather_gemm_kernel(
    const __hip_bfloat16* __restrict__ feat,
    const int*   __restrict__ A,
    const float* __restrict__ mask,
    const float* __restrict__ mw,
    const float* __restrict__ ctw,
    const float* __restrict__ ctb,
    const float* __restrict__ bias,
    float*       __restrict__ out)
{
    __shared__ float pooled[OTILE][NC];  // 32 KB
    __shared__ float ctl[32 * 33];       // padded: bank = (dout + c) % 32

    const int l  = threadIdx.x;          // 0..255
    const int o0 = blockIdx.x * OTILE;   // 512 blocks

    // Stage ct_weight into padded LDS.
    for (int i = l; i < 32 * 32; i += 256) {
        int dout = i >> 5, c = i & 31;
        ctl[dout * 33 + c] = ctw[i];
    }

    // Gather phase: thread handles nc = 2l, 2l+1.
    for (int o = 0; o < OTILE; ++o) {
        const int oo = o0 + o;
        float a0 = 0.f, a1 = 0.f;
        #pragma unroll
        for (int d = 0; d < MAXD; ++d) {
            int   j = A[oo * MAXD + d] & (INN - 1);           // wave-uniform
            float w = mw[oo * MAXD + d] * mask[oo * MAXD + d]; // wave-uniform
            __hip_bfloat162 p = *reinterpret_cast<const __hip_bfloat162*>(
                feat + (size_t)j * NC + 2 * l);
            a0 += w * __bfloat162float(p.x);
            a1 += w * __bfloat162float(p.y);
        }
        *reinterpret_cast<float2*>(&pooled[o][2 * l]) = make_float2(a0, a1);
    }
    __syncthreads();

    // GEMM phase: 512 (n,dout) pairs, 256 threads -> 2 n's per thread.
    const int dout = l & 31;
    const float cb = ctb[dout];
    #pragma unroll
    for (int h = 0; h < 2; ++h) {
        const int n = (l >> 5) + 8 * h;   // 0..15
        float vals[OTILE];
        #pragma unroll
        for (int o = 0; o < OTILE; ++o) {
            float s = cb;
            #pragma unroll
            for (int c = 0; c < 32; ++c)
                s += pooled[o][n * 32 + c] * ctl[dout * 33 + c];  // pooled: broadcast read
            vals[o] = s + bias[(size_t)dout * OUTN + o0 + o];
        }
        float4* outp = reinterpret_cast<float4*>(
            out + ((size_t)(n * 32 + dout)) * OUTN + o0);
        #pragma unroll
        for (int q = 0; q < 4; ++q)
            outp[q] = make_float4(vals[4*q], vals[4*q+1], vals[4*q+2], vals[4*q+3]);
    }
}

extern "C" void kernel_launch(void* const* d_in, const int* in_sizes, int n_in,
                              void* d_out, int out_size, void* d_ws, size_t ws_size,
                              hipStream_t stream)
{
    const float* x      = (const float*)d_in[0];   // (16,32,65536)
    const int*   A      = (const int*)  d_in[1];   // (8192,16)
    const float* weight = (const float*)d_in[2];   // (32,65536)
    const float* mask   = (const float*)d_in[3];   // (8192,16,1)
    const float* mw     = (const float*)d_in[4];   // (8192,16,1)
    const float* ctw    = (const float*)d_in[5];   // (32,32)
    const float* ctb    = (const float*)d_in[6];   // (32,)
    const float* bias   = (const float*)d_in[7];   // (32,8192)
    float* out = (float*)d_out;                    // (16,32,8192)

    __hip_bfloat16* feat = (__hip_bfloat16*)d_ws;  // (65536, 512) bf16 = 67 MB

    dim3 gA(INN / 64, NC / 64);                    // 1024 x 8
    transpose_scale_kernel<<<gA, 256, 0, stream>>>(x, weight, feat);

    gather_gemm_kernel<<<OUTN / OTILE, 256, 0, stream>>>(
        feat, A, mask, mw, ctw, ctb, bias, out);
}

// Round 2
// 258.715 us; speedup vs baseline: 1.1238x; 1.1238x over previous
//
#include <hip/hip_runtime.h>
#include <hip/hip_bf16.h>

// Problem constants
#define NN    16      // batch
#define INC   32
#define INN   65536
#define OUTC  32
#define OUTN  8192
#define MAXD  16
#define NC    512     // NN*INC

typedef __attribute__((ext_vector_type(8))) unsigned short ushort8;

// ---------------------------------------------------------------------------
// Kernel A: feat[j][r] = x[r][j] * weight[r&31][j], stored bf16 (as ushort).
// x is (512, 65536) row-major; feat is (65536, 512) row-major in d_ws.
// 64(j) x 64(r) tile. LDS tile stored [j][r] with stride 65 (2-way conflicts
// only, which are free). Global reads float4/lane, writes 16B/lane.
// ---------------------------------------------------------------------------
__global__ __launch_bounds__(256) void transpose_scale_kernel(
    const float* __restrict__ x,
    const float* __restrict__ weight,
    unsigned short* __restrict__ feat)
{
    __shared__ float tile[64][65];       // [j][r], row stride 65 floats
    const int l  = threadIdx.x;          // 0..255
    const int j0 = blockIdx.x * 64;      // 1024 blocks
    const int r0 = blockIdx.y * 64;      // 8 blocks

    // Read phase: 4 iters; each iter a wave covers 4 r-rows x 256B of j.
    #pragma unroll
    for (int it = 0; it < 4; ++it) {
        int idx = it * 256 + l;          // 0..1023
        int rl  = idx >> 4;              // 0..63
        int jj  = idx & 15;              // float4 group along j
        int r   = r0 + rl;
        int c   = r & 31;
        int j   = j0 + jj * 4;
        float4 xv = *reinterpret_cast<const float4*>(x + (size_t)r * INN + j);
        float4 wv = *reinterpret_cast<const float4*>(weight + (size_t)c * INN + j);
        tile[jj * 4 + 0][rl] = xv.x * wv.x;
        tile[jj * 4 + 1][rl] = xv.y * wv.y;
        tile[jj * 4 + 2][rl] = xv.z * wv.z;
        tile[jj * 4 + 3][rl] = xv.w * wv.w;
    }
    __syncthreads();

    // Write phase: 2 passes; 8 lanes per j-row, 8 consecutive r per lane.
    #pragma unroll
    for (int p = 0; p < 2; ++p) {
        int jl = p * 32 + (l >> 3);      // 0..63
        int rs = (l & 7) * 8;            // 0..56
        ushort8 pk;
        #pragma unroll
        for (int k = 0; k < 8; ++k) {
            float v = tile[jl][rs + k];
            pk[k] = __bfloat16_as_ushort(__float2bfloat16(v));
        }
        *reinterpret_cast<ushort8*>(
            feat + (size_t)(j0 + jl) * NC + r0 + rs) = pk;
    }
}

// ---------------------------------------------------------------------------
// Kernel B: one block per OTILE=16 output nodes.
// Gather phase: wave w handles o = 4w+i; 64 lanes x 16B = one full 1KB feat
// row per load instruction; 16 independent loads in flight per o.
// GEMM phase: ct_weight row in registers, pooled via b128 broadcast reads.
// ---------------------------------------------------------------------------
#define OTILE 16

__global__ __launch_bounds__(256) void gather_gemm_kernel(
    const unsigned short* __restrict__ feat,
    const int*   __restrict__ A,
    const float* __restrict__ mask,
    const float* __restrict__ mw,
    const float* __restrict__ ctw,
    const float* __restrict__ ctb,
    const float* __restrict__ bias,
    float*       __restrict__ out)
{
    __shared__ float pooled[OTILE][NC];  // 32 KB
    const int l    = threadIdx.x;        // 0..255
    const int wave = l >> 6;             // 0..3
    const int lane = l & 63;
    const int o0   = blockIdx.x * OTILE; // 512 blocks

    // ct_weight row for this thread's dout, into registers (8 x float4).
    const int dout = l & 31;
    float ctr[32];
    #pragma unroll
    for (int q = 0; q < 8; ++q)
        *reinterpret_cast<float4*>(&ctr[4 * q]) =
            *reinterpret_cast<const float4*>(ctw + dout * 32 + 4 * q);
    const float cb = ctb[dout];

    // Gather phase.
    #pragma unroll
    for (int i = 0; i < 4; ++i) {
        const int o  = wave * 4 + i;
        const int oo = o0 + o;
        float acc[8] = {0.f, 0.f, 0.f, 0.f, 0.f, 0.f, 0.f, 0.f};
        #pragma unroll
        for (int d = 0; d < MAXD; ++d) {
            int   j = A[oo * MAXD + d] & (INN - 1);            // wave-uniform
            float w = mw[oo * MAXD + d] * mask[oo * MAXD + d]; // wave-uniform
            ushort8 p = *reinterpret_cast<const ushort8*>(
                feat + (size_t)j * NC + lane * 8);
            #pragma unroll
            for (int k = 0; k < 8; ++k)
                acc[k] += w * __uint_as_float((unsigned)p[k] << 16);
        }
        *reinterpret_cast<float4*>(&pooled[o][lane * 8]) =
            make_float4(acc[0], acc[1], acc[2], acc[3]);
        *reinterpret_cast<float4*>(&pooled[o][lane * 8 + 4]) =
            make_float4(acc[4], acc[5], acc[6], acc[7]);
    }
    __syncthreads();

    // GEMM phase: 512 (n,dout) pairs, 2 n's per thread.
    #pragma unroll
    for (int h = 0; h < 2; ++h) {
        const int n = (l >> 5) + 8 * h;  // 0..15
        float vals[OTILE];
        #pragma unroll
        for (int o = 0; o < OTILE; ++o) {
            float s = cb;
            #pragma unroll
            for (int q = 0; q < 8; ++q) {
                float4 pv = *reinterpret_cast<const float4*>(
                    &pooled[o][n * 32 + 4 * q]);        // broadcast read
                s += pv.x * ctr[4 * q + 0] + pv.y * ctr[4 * q + 1]
                   + pv.z * ctr[4 * q + 2] + pv.w * ctr[4 * q + 3];
            }
            vals[o] = s + bias[(size_t)dout * OUTN + o0 + o];
        }
        float4* outp = reinterpret_cast<float4*>(
            out + ((size_t)(n * 32 + dout)) * OUTN + o0);
        #pragma unroll
        for (int q = 0; q < 4; ++q)
            outp[q] = make_float4(vals[4*q], vals[4*q+1], vals[4*q+2], vals[4*q+3]);
    }
}

extern "C" void kernel_launch(void* const* d_in, const int* in_sizes, int n_in,
                              void* d_out, int out_size, void* d_ws, size_t ws_size,
                              hipStream_t stream)
{
    const float* x      = (const float*)d_in[0];   // (16,32,65536)
    const int*   A      = (const int*)  d_in[1];   // (8192,16)
    const float* weight = (const float*)d_in[2];   // (32,65536)
    const float* mask   = (const float*)d_in[3];   // (8192,16,1)
    const float* mw     = (const float*)d_in[4];   // (8192,16,1)
    const float* ctw    = (const float*)d_in[5];   // (32,32)
    const float* ctb    = (const float*)d_in[6];   // (32,)
    const float* bias   = (const float*)d_in[7];   // (32,8192)
    float* out = (float*)d_out;                    // (16,32,8192)

    unsigned short* feat = (unsigned short*)d_ws;  // (65536, 512) bf16 = 67 MB

    dim3 gA(INN / 64, NC / 64);                    // 1024 x 8
    transpose_scale_kernel<<<gA, 256, 0, stream>>>(x, weight, feat);

    gather_gemm_kernel<<<OUTN / OTILE, 256, 0, stream>>>(
        feat, A, mask, mw, ctw, ctb, bias, out);
}